// Round 17
// baseline (227.203 us; speedup 1.0000x reference)
//
#include <hip/hip_runtime.h>
#include <hip/hip_bf16.h>

typedef __attribute__((ext_vector_type(8))) short short8;
typedef __attribute__((ext_vector_type(8))) unsigned short u16x8;
typedef __attribute__((ext_vector_type(4))) float f32x4;
typedef __attribute__((ext_vector_type(16))) float f32x16;

#define HIDDEN 2048
#define NH 16
#define NKV 8
#define HD 128
#define T_SEQ 2048
#define B_SZ 2
#define M_TOK (B_SZ * T_SEQ)         // 4096
#define QSIZE (NH * HD)              // 2048
#define KVSIZE (NKV * HD)            // 1024
#define OUTQKV (QSIZE + 2 * KVSIZE)  // 4096

__device__ __forceinline__ unsigned short f2bf(float f) {
  unsigned int u = __builtin_bit_cast(unsigned int, f);
  u += 0x7FFFu + ((u >> 16) & 1u);   // round-to-nearest-even
  return (unsigned short)(u >> 16);
}
__device__ __forceinline__ float bf2f(unsigned short h) {
  return __builtin_bit_cast(float, (unsigned int)h << 16);
}

typedef __attribute__((address_space(3))) void lds_void;
typedef __attribute__((address_space(1))) const void glb_void;
__device__ __forceinline__ void gld16(const void* g, void* l) {
  __builtin_amdgcn_global_load_lds((glb_void*)g, (lds_void*)l, 16, 0, 0);
}

__device__ __forceinline__ float exp2fast(float x) {
  float r;
  asm("v_exp_f32 %0, %1" : "=v"(r) : "v"(x));
  return r;
}
__device__ __forceinline__ unsigned cvtpk(float lo, float hi) {
  unsigned r;
  asm("v_cvt_pk_bf16_f32 %0, %1, %2" : "=v"(r) : "v"(lo), "v"(hi));
  return r;
}
__device__ __forceinline__ void pl32swap(unsigned& a, unsigned& b) {
  asm volatile("v_permlane32_swap_b32 %0, %1" : "+v"(a), "+v"(b));
}

template <int N>
__device__ __forceinline__ void vwait();
template <> __device__ __forceinline__ void vwait<0>() { asm volatile("s_waitcnt vmcnt(0)" ::: "memory"); }
template <> __device__ __forceinline__ void vwait<3>() { asm volatile("s_waitcnt vmcnt(3)" ::: "memory"); }
template <> __device__ __forceinline__ void vwait<4>() { asm volatile("s_waitcnt vmcnt(4)" ::: "memory"); }
template <> __device__ __forceinline__ void vwait<6>() { asm volatile("s_waitcnt vmcnt(6)" ::: "memory"); }
template <> __device__ __forceinline__ void vwait<8>() { asm volatile("s_waitcnt vmcnt(8)" ::: "memory"); }

// vectorized C-tile store: lane holds 4 consecutive columns of row-major C
__device__ __forceinline__ void store4(unsigned short* p, const f32x4& v) {
  ushort4 o;
  o.x = f2bf(v[0]); o.y = f2bf(v[1]); o.z = f2bf(v[2]); o.w = f2bf(v[3]);
  *(ushort4*)p = o;
}
__device__ __forceinline__ void store4(float* p, const f32x4& v) {
  float4 o = {v[0], v[1], v[2], v[3]};
  *(float4*)p = o;
}

// ---------------- fused prep: cvt hidden/w_qkv/w_o -> bf16 ----------------
#define SEG0 1048576           // hidden: 8.4M f32 / 8
#define SEG1 1048576           // w_qkv
#define SEG2 524288            // w_o: 4.2M f32 / 8
__global__ __launch_bounds__(256) void prep_kernel(const float* __restrict__ hidden,
                                                   const float* __restrict__ w_qkv,
                                                   const float* __restrict__ w_o,
                                                   unsigned short* __restrict__ hb,
                                                   unsigned short* __restrict__ wqkvb,
                                                   unsigned short* __restrict__ wob) {
  size_t i = (size_t)blockIdx.x * blockDim.x + threadIdx.x;
  const float* src;
  unsigned short* dst;
  if (i < SEG0) { src = hidden; dst = hb; }
  else if (i < SEG0 + SEG1) { src = w_qkv; dst = wqkvb; i -= SEG0; }
  else { src = w_o; dst = wob; i -= (SEG0 + SEG1); }
  const float4* p = (const float4*)src + i * 2;
  float4 a = p[0], b = p[1];
  u16x8 o = {f2bf(a.x), f2bf(a.y), f2bf(a.z), f2bf(a.w),
             f2bf(b.x), f2bf(b.y), f2bf(b.z), f2bf(b.w)};
  ((u16x8*)dst)[i] = o;
}

// ---------------- BMx256 GEMM, distance-3 half-tile pipeline: C = A[M,K] x B[N,K]^T --------
// Flat half-tile phases. Phase p: {ds_read slot p&3 (B 4 + A MT2, then A high MT2);
// stage h(p+3) -> slot (p+3)&3; vmcnt(2*LPH) drains h(p+1) [cover = 2 phases > L2/HBM lat];
// MFMA; raw s_barrier}. Slots in play {p, p+1, p+2, p+3} all distinct mod 4. Never drains
// to 0 mid-loop. K-order per acc unchanged -> bit-identical vs prior rounds.
template <int MT, typename TC>
__global__ __launch_bounds__(512, 2) void gemm8(const unsigned short* __restrict__ A,
                                                const unsigned short* __restrict__ B,
                                                TC* __restrict__ C,
                                                int M, int N, int K) {
  constexpr int BM = MT * 32;
  constexpr int MT2 = MT / 2;
  constexpr int LPH = (MT == 8) ? 4 : 3;   // global_load_lds per half-tile (A+B)
  __shared__ unsigned short lsA[4][BM * 32];
  __shared__ unsigned short lsB[4][8192];
  const int tid = threadIdx.x;
  const int wave = tid >> 6, lane = tid & 63;
  const int wr = wave >> 2, wc = wave & 3;       // 2 x 4 waves, (MT*16)x64 C each
  const int lr = lane & 15;
  const int ntn = N >> 8;
  const int cpx = gridDim.x >> 3;                // bijective XCD swizzle (grid % 8 == 0)
  const int wg = (blockIdx.x & 7) * cpx + (blockIdx.x >> 3);
  const int m0 = (wg / ntn) * BM, n0 = (wg % ntn) * 256;
  const int ce = 8 * ((lane >> 4) ^ ((lr >> 1) & 3));
  const int rr0 = tid >> 2;
  const int cle = 8 * ((tid & 3) ^ ((rr0 >> 1) & 3));
  const unsigned short* pA0 = A + (size_t)(m0 + rr0) * K + cle;
  const unsigned short* pA1 = pA0 + (size_t)128 * K;
  const unsigned short* pB0 = B + (size_t)(n0 + rr0) * K + cle;
  const unsigned short* pB1 = pB0 + (size_t)128 * K;
  const int dst0 = 8 * tid, dst1 = 4096 + 8 * tid;

  auto stageH = [&](int hn) {                    // half-tile hn -> slot hn&3
    const int s = hn & 3;
    gld16(pA0 + hn * 32, &lsA[s][dst0]);
    if constexpr (MT == 8) gld16(pA1 + hn * 32, &lsA[s][dst1]);
    gld16(pB0 + hn * 32, &lsB[s][dst0]);
    gld16(pB1 + hn * 32, &lsB[s][dst1]);
  };

  f32x4 acc[MT][4] = {};
  short8 af[MT2], bfg[4];
  const int NT2 = K >> 5;                        // 32-wide half-tiles (>= 4 here)

  stageH(0); stageH(1); stageH(2);
  vwait<2 * LPH>();                              // h0 landed; h1,h2 in flight
  __builtin_amdgcn_s_barrier();

  for (int p = 0; p < NT2; p++) {
    const int slot = p & 3;
#pragma unroll
    for (int j = 0; j < 4; j++)
      bfg[j] = *(const short8*)&lsB[slot][(wc * 64 + j * 16 + lr) * 32 + ce];
#pragma unroll
    for (int i = 0; i < MT2; i++)
      af[i] = *(const short8*)&lsA[slot][(wr * (MT * 16) + i * 16 + lr) * 32 + ce];
    if (p + 3 < NT2) stageH(p + 3);
    if (p < NT2 - 3) vwait<2 * LPH>();           // drain h(p+1); keep h(p+2),h(p+3)
    else if (p == NT2 - 3) vwait<LPH>();         // drain h(p+1); keep h(p+2)
    else vwait<0>();
    __builtin_amdgcn_s_setprio(1);
#pragma unroll
    for (int i = 0; i < MT2; i++)
#pragma unroll
      for (int j = 0; j < 4; j++)
        acc[i][j] = __builtin_amdgcn_mfma_f32_16x16x32_bf16(bfg[j], af[i], acc[i][j], 0, 0, 0);
    __builtin_amdgcn_s_setprio(0);
#pragma unroll
    for (int i = 0; i < MT2; i++)
      af[i] = *(const short8*)&lsA[slot][(wr * (MT * 16) + MT * 8 + i * 16 + lr) * 32 + ce];
    __builtin_amdgcn_s_setprio(1);
#pragma unroll
    for (int i = 0; i < MT2; i++)
#pragma unroll
      for (int j = 0; j < 4; j++)
        acc[MT2 + i][j] = __builtin_amdgcn_mfma_f32_16x16x32_bf16(bfg[j], af[i], acc[MT2 + i][j], 0, 0, 0);
    __builtin_amdgcn_s_setprio(0);
    __builtin_amdgcn_s_barrier();
  }

#pragma unroll
  for (int i = 0; i < MT; i++)
#pragma unroll
    for (int j = 0; j < 4; j++) {
      int gm = m0 + wr * (MT * 16) + i * 16 + lr;           // C row
      int gn = n0 + wc * 64 + j * 16 + (lane >> 4) * 4;     // 4 consecutive C cols
      store4(C + (size_t)gm * N + gn, acc[i][j]);
    }
}

// ---------------- per-head RMSNorm + NeoX RoPE (q,k only) ----------------
__global__ void norm_rope_kernel(const unsigned short* __restrict__ qkv,
                                 const int* __restrict__ positions,
                                 const float* __restrict__ rms_w,
                                 unsigned short* __restrict__ qa,
                                 unsigned short* __restrict__ ka) {
  const int m = blockIdx.x;
  const int b = m >> 11, tt = m & 2047;
  const int lane = threadIdx.x;
  const float pos = (float)positions[m];
  const float inv_freq = powf(10000.0f, -(float)lane * (1.0f / 64.0f));
  float sv, cv;
  sincosf(pos * inv_freq, &sv, &cv);
  const float w1 = rms_w[lane], w2 = rms_w[lane + 64];
  const unsigned short* src = qkv + (size_t)m * OUTQKV;
  for (int h = 0; h < 24; h++) {
    unsigned short r1 = src[h * 128 + lane], r2 = src[h * 128 + 64 + lane];
    float x1 = bf2f(r1), x2 = bf2f(r2);
    float ss = x1 * x1 + x2 * x2;
    ss += __shfl_xor(ss, 1);  ss += __shfl_xor(ss, 2);  ss += __shfl_xor(ss, 4);
    ss += __shfl_xor(ss, 8);  ss += __shfl_xor(ss, 16); ss += __shfl_xor(ss, 32);
    float rstd = rsqrtf(ss * (1.0f / 128.0f) + 1e-6f);
    float y1 = x1 * rstd * w1, y2 = x2 * rstd * w2;
    float o1 = y1 * cv - y2 * sv, o2 = y2 * cv + y1 * sv;
    unsigned short* dst;
    if (h < 16) dst = qa + (((size_t)b * NH + h) * T_SEQ + tt) * HD;
    else        dst = ka + (((size_t)b * NKV + (h - 16)) * T_SEQ + tt) * HD;
    dst[lane] = f2bf(o1); dst[lane + 64] = f2bf(o2);
  }
}

// ---------------- V transpose: qkv v-section -> vat[b][kvh][d][T] ----------------
__global__ __launch_bounds__(256) void v_transpose(const unsigned short* __restrict__ qkv,
                                                   unsigned short* __restrict__ vat) {
  __shared__ unsigned short tile[64][136];
  const int tt0 = blockIdx.x * 64;
  const int kvh = blockIdx.y, b = blockIdx.z;
  const int t = threadIdx.x;
  {
    const int tok = t >> 2, d0 = (t & 3) * 32;
    const unsigned short* src = qkv + (size_t)((size_t)b * T_SEQ + tt0 + tok) * OUTQKV
                                + QSIZE + KVSIZE + kvh * HD + d0;
#pragma unroll
    for (int i = 0; i < 4; i++)
      *(u16x8*)&tile[tok][d0 + i * 8] = *(const u16x8*)(src + i * 8);
  }
  __syncthreads();
  {
    const int d = t >> 1, c0 = (t & 1) * 32;
    unsigned short* dst = vat + ((size_t)((size_t)b * NKV + kvh) * HD + d) * T_SEQ + tt0 + c0;
#pragma unroll
    for (int j = 0; j < 4; j++) {
      u16x8 v;
#pragma unroll
      for (int e = 0; e < 8; e++) v[e] = tile[c0 + j * 8 + e][d];
      *(u16x8*)(dst + j * 8) = v;
    }
  }
}

// ---------------- flash attention (round-16: pair-sum-balanced dispatch) --------------------
__global__ __launch_bounds__(256, 2) void attn_kernel(const unsigned short* __restrict__ qa,
                                                      const unsigned short* __restrict__ ka,
                                                      const unsigned short* __restrict__ vat,
                                                      unsigned short* __restrict__ ob) {
  __shared__ unsigned short ks[2][64 * 128];
  __shared__ unsigned short vs[2][128 * 64];
  const int bx = blockIdx.x;
  const int qt = (bx < 256) ? (31 - (bx >> 4)) : ((bx - 256) >> 4);
  const int kvh = bx & 7, b = (bx >> 3) & 1;
  const int tid = threadIdx.x, w = tid >> 6, lane = tid & 63;
  const int l31 = lane & 31, h5 = lane >> 5;
  const int h = kvh * 2 + (w >> 1);
  const int qrow = qt * 64 + (w & 1) * 32 + l31;
  const float cexp = 0.08838834764831845f * 1.44269504088896340f;  // scale * log2(e)

  const unsigned short* Kg = ka + ((size_t)b * NKV + kvh) * T_SEQ * HD;
  const unsigned short* Vg = vat + ((size_t)b * NKV + kvh) * (size_t)HD * T_SEQ;

  short8 qf[8];
  {
    const unsigned short* Qg = qa + (((size_t)b * NH + h) * T_SEQ + qrow) * HD;
#pragma unroll
    for (int c = 0; c < 8; c++) qf[c] = *(const short8*)(Qg + c * 16 + h5 * 8);
  }

  auto stage = [&](int j, int buf) {
#pragma unroll
    for (int s = 0; s < 4; s++) {
      int g = s * 256 + tid;
      int kr = g >> 4;
      int kc = 8 * ((g & 15) ^ (kr & 15));
      gld16(Kg + (size_t)(j * 64 + kr) * HD + kc, &ks[buf][g * 8]);
    }
#pragma unroll
    for (int s = 0; s < 4; s++) {
      int g = s * 256 + tid;
      int vd = g >> 3;
      int vc = 8 * ((g & 7) ^ (vd & 7));
      gld16(Vg + (size_t)vd * T_SEQ + j * 64 + vc, &vs[buf][g * 8]);
    }
  };

  stage(0, 0);
  vwait<0>();
  __syncthreads();

  f32x16 oacc[4] = {};
  float mraw = -1e30f, m2 = -3.0e29f, lsum = 0.f;

  for (int j = 0; j <= qt; j++) {
    const int buf = j & 1;
    if (j < qt) stage(j + 1, buf ^ 1);

    f32x16 sacc[2] = {};
    __builtin_amdgcn_s_setprio(1);
#pragma unroll
    for (int c = 0; c < 8; c++) {
#pragma unroll
      for (int t = 0; t < 2; t++) {
        const int row = t * 32 + l31;
        short8 kf = *(const short8*)&ks[buf][row * 128 + ((c * 16 + h5 * 8) ^ (8 * (l31 & 15)))];
        sacc[t] = __builtin_amdgcn_mfma_f32_32x32x16_bf16(kf, qf[c], sacc[t], 0, 0, 0);
      }
    }
    __builtin_amdgcn_s_setprio(0);

    if (j * 64 + 63 > qt * 64 + (w & 1) * 32) {
#pragma unroll
      for (int t = 0; t < 2; t++)
#pragma unroll
        for (int r = 0; r < 16; r++) {
          int kvg = j * 64 + t * 32 + (r & 3) + 8 * (r >> 2) + 4 * h5;
          if (kvg > qrow) sacc[t][r] = -1e30f;
        }
    }
    float mx = sacc[0][0];
#pragma unroll
    for (int t = 0; t < 2; t++)
#pragma unroll
      for (int r = 0; r < 16; r++) mx = fmaxf(mx, sacc[t][r]);
    mx = fmaxf(mx, __shfl_xor(mx, 32));
    if (__any((mx - mraw) * cexp > 11.5f)) {  // T13 defer-max
      float mn = fmaxf(mraw, mx);
      float corr = exp2fast((mraw - mn) * cexp);
      mraw = mn;
      m2 = mn * cexp;
      lsum *= corr;
#pragma unroll
      for (int dt = 0; dt < 4; dt++)
#pragma unroll
        for (int r = 0; r < 16; r++) oacc[dt][r] *= corr;
    }
    short8 pf[4];
#pragma unroll
    for (int kt = 0; kt < 4; kt++) {
      const int t = kt >> 1, r0 = (kt & 1) * 8;
      float e0 = exp2fast(sacc[t][r0 + 0] * cexp - m2);
      float e1 = exp2fast(sacc[t][r0 + 1] * cexp - m2);
      float e2 = exp2fast(sacc[t][r0 + 2] * cexp - m2);
      float e3 = exp2fast(sacc[t][r0 + 3] * cexp - m2);
      float e4 = exp2fast(sacc[t][r0 + 4] * cexp - m2);
      float e5 = exp2fast(sacc[t][r0 + 5] * cexp - m2);
      float e6 = exp2fast(sacc[t][r0 + 6] * cexp - m2);
      float e7 = exp2fast(sacc[t][r0 + 7] * cexp - m2);
      lsum += ((e0 + e1) + (e2 + e3)) + ((e4 + e5) + (e6 + e7));
      unsigned a0 = cvtpk(e0, e1), a1 = cvtpk(e2, e3);
      unsigned b0 = cvtpk(e4, e5), b1 = cvtpk(e6, e7);
      pl32swap(a0, b0);
      pl32swap(a1, b1);
      uint4 uu = make_uint4(a0, a1, b0, b1);
      pf[kt] = __builtin_bit_cast(short8, uu);
    }
    __builtin_amdgcn_s_setprio(1);
#pragma unroll
    for (int dt = 0; dt < 4; dt++) {
      const int d = dt * 32 + l31;
#pragma unroll
      for (int kt = 0; kt < 4; kt++) {
        short8 vf = *(const short8*)&vs[buf][d * 64 + ((kt * 16 + h5 * 8) ^ (8 * (l31 & 7)))];
        oacc[dt] = __builtin_amdgcn_mfma_f32_32x32x16_bf16(vf, pf[kt], oacc[dt], 0, 0, 0);
      }
    }
    __builtin_amdgcn_s_setprio(0);
    vwait<0>();
    __syncthreads();
  }

  lsum += __shfl_xor(lsum, 32);
  const float inv = 1.0f / lsum;
  unsigned short* dst = ob + ((size_t)b * T_SEQ + qrow) * QSIZE + h * HD;
#pragma unroll
  for (int dt = 0; dt < 4; dt++)
#pragma unroll
    for (int rg = 0; rg < 4; rg++) {
      ushort4 v4;
      v4.x = f2bf(oacc[dt][rg * 4 + 0] * inv);
      v4.y = f2bf(oacc[dt][rg * 4 + 1] * inv);
      v4.z = f2bf(oacc[dt][rg * 4 + 2] * inv);
      v4.w = f2bf(oacc[dt][rg * 4 + 3] * inv);
      *(ushort4*)(dst + dt * 32 + rg * 8 + 4 * h5) = v4;
    }
}

// ---------------- launch ----------------
extern "C" void kernel_launch(void* const* d_in, const int* in_sizes, int n_in,
                              void* d_out, int out_size, void* d_ws, size_t ws_size,
                              hipStream_t stream) {
  const int* positions = (const int*)d_in[0];
  const float* hidden  = (const float*)d_in[1];
  const float* w_qkv   = (const float*)d_in[2];
  const float* w_o     = (const float*)d_in[3];
  const float* rms_w   = (const float*)d_in[4];
  float* out = (float*)d_out;

  // byte layout (72 MB): [qkv 32M][hb 16M][wqkvb 16M][wob 8M]
  unsigned short* qkv   = (unsigned short*)d_ws;                   // [4096][4096]
  unsigned short* hb    = qkv + (size_t)M_TOK * OUTQKV;            // [4096][2048]
  unsigned short* wqkvb = hb + (size_t)M_TOK * HIDDEN;             // [4096][2048]
  unsigned short* wob   = wqkvb + (size_t)OUTQKV * HIDDEN;         // [2048][2048]
  unsigned short* qa    = hb;                                      // alias after gemm1
  unsigned short* ka    = wqkvb;                                   // alias after gemm1
  unsigned short* vat   = wqkvb + (size_t)B_SZ * NKV * T_SEQ * HD;
  unsigned short* ob    = qkv;                                     // alias after v_transpose

  const int prep_items = SEG0 + SEG1 + SEG2;
  prep_kernel<<<prep_items / 256, 256, 0, stream>>>(hidden, w_qkv, w_o, hb, wqkvb, wob);
  gemm8<8, unsigned short>
      <<<256, 512, 0, stream>>>(hb, wqkvb, qkv, M_TOK, OUTQKV, HIDDEN);
  norm_rope_kernel<<<M_TOK, 64, 0, stream>>>(qkv, positions, rms_w, qa, ka);
  v_transpose<<<dim3(T_SEQ / 64, NKV, B_SZ), 256, 0, stream>>>(qkv, vat);
  attn_kernel<<<512, 256, 0, stream>>>(qa, ka, vat, ob);
  gemm8<4, float>
      <<<256, 512, 0, stream>>>(ob, wob, out, M_TOK, HIDDEN, QSIZE);
}

// Round 18
// 209.570 us; speedup vs baseline: 1.0841x; 1.0841x over previous
//
#include <hip/hip_runtime.h>
#include <hip/hip_bf16.h>

typedef __attribute__((ext_vector_type(8))) short short8;
typedef __attribute__((ext_vector_type(8))) unsigned short u16x8;
typedef __attribute__((ext_vector_type(4))) float f32x4;
typedef __attribute__((ext_vector_type(16))) float f32x16;

#define HIDDEN 2048
#define NH 16
#define NKV 8
#define HD 128
#define T_SEQ 2048
#define B_SZ 2
#define M_TOK (B_SZ * T_SEQ)         // 4096
#define QSIZE (NH * HD)              // 2048
#define KVSIZE (NKV * HD)            // 1024
#define OUTQKV (QSIZE + 2 * KVSIZE)  // 4096

__device__ __forceinline__ unsigned short f2bf(float f) {
  unsigned int u = __builtin_bit_cast(unsigned int, f);
  u += 0x7FFFu + ((u >> 16) & 1u);   // round-to-nearest-even
  return (unsigned short)(u >> 16);
}
__device__ __forceinline__ float bf2f(unsigned short h) {
  return __builtin_bit_cast(float, (unsigned int)h << 16);
}

typedef __attribute__((address_space(3))) void lds_void;
typedef __attribute__((address_space(1))) const void glb_void;
__device__ __forceinline__ void gld16(const void* g, void* l) {
  __builtin_amdgcn_global_load_lds((glb_void*)g, (lds_void*)l, 16, 0, 0);
}

__device__ __forceinline__ float exp2fast(float x) {
  float r;
  asm("v_exp_f32 %0, %1" : "=v"(r) : "v"(x));
  return r;
}
__device__ __forceinline__ unsigned cvtpk(float lo, float hi) {
  unsigned r;
  asm("v_cvt_pk_bf16_f32 %0, %1, %2" : "=v"(r) : "v"(lo), "v"(hi));
  return r;
}
__device__ __forceinline__ void pl32swap(unsigned& a, unsigned& b) {
  asm volatile("v_permlane32_swap_b32 %0, %1" : "+v"(a), "+v"(b));
}

template <int N>
__device__ __forceinline__ void vwait();
template <> __device__ __forceinline__ void vwait<0>() { asm volatile("s_waitcnt vmcnt(0)" ::: "memory"); }
template <> __device__ __forceinline__ void vwait<3>() { asm volatile("s_waitcnt vmcnt(3)" ::: "memory"); }
template <> __device__ __forceinline__ void vwait<4>() { asm volatile("s_waitcnt vmcnt(4)" ::: "memory"); }

// vectorized C-tile store: lane holds 4 consecutive columns of row-major C
__device__ __forceinline__ void store4(unsigned short* p, const f32x4& v) {
  ushort4 o;
  o.x = f2bf(v[0]); o.y = f2bf(v[1]); o.z = f2bf(v[2]); o.w = f2bf(v[3]);
  *(ushort4*)p = o;
}
__device__ __forceinline__ void store4(float* p, const f32x4& v) {
  float4 o = {v[0], v[1], v[2], v[3]};
  *(float4*)p = o;
}

// ---------------- fused prep: cvt hidden/w_qkv/w_o -> bf16 ----------------
#define SEG0 1048576           // hidden: 8.4M f32 / 8
#define SEG1 1048576           // w_qkv
#define SEG2 524288            // w_o: 4.2M f32 / 8
__global__ __launch_bounds__(256) void prep_kernel(const float* __restrict__ hidden,
                                                   const float* __restrict__ w_qkv,
                                                   const float* __restrict__ w_o,
                                                   unsigned short* __restrict__ hb,
                                                   unsigned short* __restrict__ wqkvb,
                                                   unsigned short* __restrict__ wob) {
  size_t i = (size_t)blockIdx.x * blockDim.x + threadIdx.x;
  const float* src;
  unsigned short* dst;
  if (i < SEG0) { src = hidden; dst = hb; }
  else if (i < SEG0 + SEG1) { src = w_qkv; dst = wqkvb; i -= SEG0; }
  else { src = w_o; dst = wob; i -= (SEG0 + SEG1); }
  const float4* p = (const float4*)src + i * 2;
  float4 a = p[0], b = p[1];
  u16x8 o = {f2bf(a.x), f2bf(a.y), f2bf(a.z), f2bf(a.w),
             f2bf(b.x), f2bf(b.y), f2bf(b.z), f2bf(b.w)};
  ((u16x8*)dst)[i] = o;
}

// ---------------- BMx256 merged-phase GEMM: C = A[M,K] x B[N,K]^T ----------------
// MT = 16-row M-subtiles per wave; BM = MT*32 (8 -> 256x256, 4 -> 128x256).
// TWO phases per K-tile; each phase reads B once + A for both M-halves, stages one K-half,
// counted vmcnt (never 0 mid-loop), ONE barrier. Best-measured GEMM schedule of this session.
template <int MT, typename TC>
__global__ __launch_bounds__(512, 2) void gemm8(const unsigned short* __restrict__ A,
                                                const unsigned short* __restrict__ B,
                                                TC* __restrict__ C,
                                                int M, int N, int K) {
  constexpr int BM = MT * 32;
  constexpr int MT2 = MT / 2;
  constexpr int VMN = (MT == 8) ? 4 : 3;
  __shared__ unsigned short lsA[4][BM * 32];
  __shared__ unsigned short lsB[4][8192];
  const int tid = threadIdx.x;
  const int wave = tid >> 6, lane = tid & 63;
  const int wr = wave >> 2, wc = wave & 3;       // 2 x 4 waves, (MT*16)x64 C each
  const int lr = lane & 15;
  const int ntn = N >> 8;
  const int cpx = gridDim.x >> 3;                // bijective XCD swizzle (grid % 8 == 0)
  const int wg = (blockIdx.x & 7) * cpx + (blockIdx.x >> 3);
  const int m0 = (wg / ntn) * BM, n0 = (wg % ntn) * 256;
  const int ce = 8 * ((lane >> 4) ^ ((lr >> 1) & 3));
  const int rr0 = tid >> 2;
  const int cle = 8 * ((tid & 3) ^ ((rr0 >> 1) & 3));
  const unsigned short* pA0 = A + (size_t)(m0 + rr0) * K + cle;
  const unsigned short* pA1 = pA0 + (size_t)128 * K;
  const unsigned short* pB0 = B + (size_t)(n0 + rr0) * K + cle;
  const unsigned short* pB1 = pB0 + (size_t)128 * K;
  const int dst0 = 8 * tid, dst1 = 4096 + 8 * tid;

  auto stageA = [&](int hn) {
    const int s = hn & 3;
    gld16(pA0 + hn * 32, &lsA[s][dst0]);
    if constexpr (MT == 8) gld16(pA1 + hn * 32, &lsA[s][dst1]);
  };
  auto stageB = [&](int hn) {
    const int s = hn & 3;
    gld16(pB0 + hn * 32, &lsB[s][dst0]);
    gld16(pB1 + hn * 32, &lsB[s][dst1]);
  };

  f32x4 acc[MT][4] = {};
  short8 af[MT2], bfg[4];
  const int NT = K >> 6;

  stageA(0); stageB(0); stageA(1); stageB(1);
  vwait<0>();
  __syncthreads();

#define PHASE2(KK)                                                                        \
  {                                                                                       \
    const int slot = (sb + (KK)) & 3;                                                     \
    _Pragma("unroll")                                                                     \
    for (int j = 0; j < 4; j++)                                                           \
      bfg[j] = *(const short8*)&lsB[slot][(wc * 64 + j * 16 + lr) * 32 + ce];             \
    _Pragma("unroll")                                                                     \
    for (int i = 0; i < MT2; i++)                                                         \
      af[i] = *(const short8*)&lsA[slot][(wr * (MT * 16) + i * 16 + lr) * 32 + ce];       \
    if (st) { stageA(h2 + (KK)); stageB(h2 + (KK)); }                                     \
    if (st) vwait<VMN>(); else vwait<0>();                                                \
    __builtin_amdgcn_s_setprio(1);                                                        \
    _Pragma("unroll")                                                                     \
    for (int i = 0; i < MT2; i++)                                                         \
      _Pragma("unroll")                                                                   \
      for (int j = 0; j < 4; j++)                                                         \
        acc[i][j] =                                                                       \
            __builtin_amdgcn_mfma_f32_16x16x32_bf16(bfg[j], af[i], acc[i][j], 0, 0, 0);   \
    __builtin_amdgcn_s_setprio(0);                                                        \
    _Pragma("unroll")                                                                     \
    for (int i = 0; i < MT2; i++)                                                         \
      af[i] = *(const short8*)&lsA[slot][(wr * (MT * 16) + MT * 8 + i * 16 + lr) * 32 + ce]; \
    __builtin_amdgcn_s_setprio(1);                                                        \
    _Pragma("unroll")                                                                     \
    for (int i = 0; i < MT2; i++)                                                         \
      _Pragma("unroll")                                                                   \
      for (int j = 0; j < 4; j++)                                                         \
        acc[MT2 + i][j] =                                                                 \
            __builtin_amdgcn_mfma_f32_16x16x32_bf16(bfg[j], af[i], acc[MT2 + i][j], 0, 0, 0); \
    __builtin_amdgcn_s_setprio(0);                                                        \
    __builtin_amdgcn_s_barrier();                                                         \
  }

  for (int t = 0; t < NT; t++) {
    const int sb = (2 * t) & 3;
    const bool st = (t < NT - 1);
    const int h2 = 2 * t + 2;
    PHASE2(0)
    PHASE2(1)
  }
#undef PHASE2

#pragma unroll
  for (int i = 0; i < MT; i++)
#pragma unroll
    for (int j = 0; j < 4; j++) {
      int gm = m0 + wr * (MT * 16) + i * 16 + lr;           // C row
      int gn = n0 + wc * 64 + j * 16 + (lane >> 4) * 4;     // 4 consecutive C cols
      store4(C + (size_t)gm * N + gn, acc[i][j]);
    }
}

// ---------------- per-head RMSNorm + NeoX RoPE (q,k only) ----------------
__global__ void norm_rope_kernel(const unsigned short* __restrict__ qkv,
                                 const int* __restrict__ positions,
                                 const float* __restrict__ rms_w,
                                 unsigned short* __restrict__ qa,
                                 unsigned short* __restrict__ ka) {
  const int m = blockIdx.x;
  const int b = m >> 11, tt = m & 2047;
  const int lane = threadIdx.x;
  const float pos = (float)positions[m];
  const float inv_freq = powf(10000.0f, -(float)lane * (1.0f / 64.0f));
  float sv, cv;
  sincosf(pos * inv_freq, &sv, &cv);
  const float w1 = rms_w[lane], w2 = rms_w[lane + 64];
  const unsigned short* src = qkv + (size_t)m * OUTQKV;
  for (int h = 0; h < 24; h++) {
    unsigned short r1 = src[h * 128 + lane], r2 = src[h * 128 + 64 + lane];
    float x1 = bf2f(r1), x2 = bf2f(r2);
    float ss = x1 * x1 + x2 * x2;
    ss += __shfl_xor(ss, 1);  ss += __shfl_xor(ss, 2);  ss += __shfl_xor(ss, 4);
    ss += __shfl_xor(ss, 8);  ss += __shfl_xor(ss, 16); ss += __shfl_xor(ss, 32);
    float rstd = rsqrtf(ss * (1.0f / 128.0f) + 1e-6f);
    float y1 = x1 * rstd * w1, y2 = x2 * rstd * w2;
    float o1 = y1 * cv - y2 * sv, o2 = y2 * cv + y1 * sv;
    unsigned short* dst;
    if (h < 16) dst = qa + (((size_t)b * NH + h) * T_SEQ + tt) * HD;
    else        dst = ka + (((size_t)b * NKV + (h - 16)) * T_SEQ + tt) * HD;
    dst[lane] = f2bf(o1); dst[lane + 64] = f2bf(o2);
  }
}

// ---------------- V transpose: qkv v-section -> vat[b][kvh][d][T] ----------------
__global__ __launch_bounds__(256) void v_transpose(const unsigned short* __restrict__ qkv,
                                                   unsigned short* __restrict__ vat) {
  __shared__ unsigned short tile[64][136];
  const int tt0 = blockIdx.x * 64;
  const int kvh = blockIdx.y, b = blockIdx.z;
  const int t = threadIdx.x;
  {
    const int tok = t >> 2, d0 = (t & 3) * 32;
    const unsigned short* src = qkv + (size_t)((size_t)b * T_SEQ + tt0 + tok) * OUTQKV
                                + QSIZE + KVSIZE + kvh * HD + d0;
#pragma unroll
    for (int i = 0; i < 4; i++)
      *(u16x8*)&tile[tok][d0 + i * 8] = *(const u16x8*)(src + i * 8);
  }
  __syncthreads();
  {
    const int d = t >> 1, c0 = (t & 1) * 32;
    unsigned short* dst = vat + ((size_t)((size_t)b * NKV + kvh) * HD + d) * T_SEQ + tt0 + c0;
#pragma unroll
    for (int j = 0; j < 4; j++) {
      u16x8 v;
#pragma unroll
      for (int e = 0; e < 8; e++) v[e] = tile[c0 + j * 8 + e][d];
      *(u16x8*)(dst + j * 8) = v;
    }
  }
}

// ---------------- flash attention: pair-balanced grid (qt_a = p, qt_b = 31-p) ----------------
// 256 blocks x 4 waves; every block does exactly 33 K-tiles -> perfect load balance.
__global__ __launch_bounds__(256, 2) void attn_kernel(const unsigned short* __restrict__ qa,
                                                      const unsigned short* __restrict__ ka,
                                                      const unsigned short* __restrict__ vat,
                                                      unsigned short* __restrict__ ob) {
  __shared__ unsigned short ks[2][64 * 128];
  __shared__ unsigned short vs[2][128 * 64];
  const int bx = blockIdx.x;
  const int pr = bx >> 4;                  // pair index 0..15
  const int kvh = bx & 7, b = (bx >> 3) & 1;
  const int tid = threadIdx.x, w = tid >> 6, lane = tid & 63;
  const int l31 = lane & 31, h5 = lane >> 5;
  const int h = kvh * 2 + (w >> 1);
  const float cexp = 0.08838834764831845f * 1.44269504088896340f;  // scale * log2(e)

  const unsigned short* Kg = ka + ((size_t)b * NKV + kvh) * T_SEQ * HD;
  const unsigned short* Vg = vat + ((size_t)b * NKV + kvh) * (size_t)HD * T_SEQ;

  auto stage = [&](int j, int buf) {
#pragma unroll
    for (int s = 0; s < 4; s++) {
      int g = s * 256 + tid;
      int kr = g >> 4;
      int kc = 8 * ((g & 15) ^ (kr & 15));
      gld16(Kg + (size_t)(j * 64 + kr) * HD + kc, &ks[buf][g * 8]);
    }
#pragma unroll
    for (int s = 0; s < 4; s++) {
      int g = s * 256 + tid;
      int vd = g >> 3;
      int vc = 8 * ((g & 7) ^ (vd & 7));
      gld16(Vg + (size_t)vd * T_SEQ + j * 64 + vc, &vs[buf][g * 8]);
    }
  };

#pragma unroll 1
  for (int pass = 0; pass < 2; pass++) {
    const int qt = pass ? (31 - pr) : pr;
    const int qrow = qt * 64 + (w & 1) * 32 + l31;

    short8 qf[8];
    {
      const unsigned short* Qg = qa + (((size_t)b * NH + h) * T_SEQ + qrow) * HD;
#pragma unroll
      for (int c = 0; c < 8; c++) qf[c] = *(const short8*)(Qg + c * 16 + h5 * 8);
    }

    stage(0, 0);
    vwait<0>();
    __syncthreads();

    f32x16 oacc[4] = {};
    float mraw = -1e30f, m2 = -3.0e29f, lsum = 0.f;

    for (int j = 0; j <= qt; j++) {
      const int buf = j & 1;
      if (j < qt) stage(j + 1, buf ^ 1);

      f32x16 sacc[2] = {};
      __builtin_amdgcn_s_setprio(1);
#pragma unroll
      for (int c = 0; c < 8; c++) {
#pragma unroll
        for (int t = 0; t < 2; t++) {
          const int row = t * 32 + l31;
          short8 kf = *(const short8*)&ks[buf][row * 128 + ((c * 16 + h5 * 8) ^ (8 * (l31 & 15)))];
          sacc[t] = __builtin_amdgcn_mfma_f32_32x32x16_bf16(kf, qf[c], sacc[t], 0, 0, 0);
        }
      }
      __builtin_amdgcn_s_setprio(0);

      if (j * 64 + 63 > qt * 64 + (w & 1) * 32) {
#pragma unroll
        for (int t = 0; t < 2; t++)
#pragma unroll
          for (int r = 0; r < 16; r++) {
            int kvg = j * 64 + t * 32 + (r & 3) + 8 * (r >> 2) + 4 * h5;
            if (kvg > qrow) sacc[t][r] = -1e30f;
          }
      }
      float mx = sacc[0][0];
#pragma unroll
      for (int t = 0; t < 2; t++)
#pragma unroll
        for (int r = 0; r < 16; r++) mx = fmaxf(mx, sacc[t][r]);
      mx = fmaxf(mx, __shfl_xor(mx, 32));
      if (__any((mx - mraw) * cexp > 11.5f)) {  // T13 defer-max
        float mn = fmaxf(mraw, mx);
        float corr = exp2fast((mraw - mn) * cexp);
        mraw = mn;
        m2 = mn * cexp;
        lsum *= corr;
#pragma unroll
        for (int dt = 0; dt < 4; dt++)
#pragma unroll
          for (int r = 0; r < 16; r++) oacc[dt][r] *= corr;
      }
      short8 pf[4];
#pragma unroll
      for (int kt = 0; kt < 4; kt++) {
        const int t = kt >> 1, r0 = (kt & 1) * 8;
        float e0 = exp2fast(sacc[t][r0 + 0] * cexp - m2);
        float e1 = exp2fast(sacc[t][r0 + 1] * cexp - m2);
        float e2 = exp2fast(sacc[t][r0 + 2] * cexp - m2);
        float e3 = exp2fast(sacc[t][r0 + 3] * cexp - m2);
        float e4 = exp2fast(sacc[t][r0 + 4] * cexp - m2);
        float e5 = exp2fast(sacc[t][r0 + 5] * cexp - m2);
        float e6 = exp2fast(sacc[t][r0 + 6] * cexp - m2);
        float e7 = exp2fast(sacc[t][r0 + 7] * cexp - m2);
        lsum += ((e0 + e1) + (e2 + e3)) + ((e4 + e5) + (e6 + e7));
        unsigned a0 = cvtpk(e0, e1), a1 = cvtpk(e2, e3);
        unsigned b0 = cvtpk(e4, e5), b1 = cvtpk(e6, e7);
        pl32swap(a0, b0);
        pl32swap(a1, b1);
        uint4 uu = make_uint4(a0, a1, b0, b1);
        pf[kt] = __builtin_bit_cast(short8, uu);
      }
      __builtin_amdgcn_s_setprio(1);
#pragma unroll
      for (int dt = 0; dt < 4; dt++) {
        const int d = dt * 32 + l31;
#pragma unroll
        for (int kt = 0; kt < 4; kt++) {
          short8 vf = *(const short8*)&vs[buf][d * 64 + ((kt * 16 + h5 * 8) ^ (8 * (l31 & 7)))];
          oacc[dt] = __builtin_amdgcn_mfma_f32_32x32x16_bf16(vf, pf[kt], oacc[dt], 0, 0, 0);
        }
      }
      __builtin_amdgcn_s_setprio(0);
      vwait<0>();
      __syncthreads();
    }

    lsum += __shfl_xor(lsum, 32);
    const float inv = 1.0f / lsum;
    unsigned short* dst = ob + ((size_t)b * T_SEQ + qrow) * QSIZE + h * HD;
#pragma unroll
    for (int dt = 0; dt < 4; dt++)
#pragma unroll
      for (int rg = 0; rg < 4; rg++) {
        ushort4 v4;
        v4.x = f2bf(oacc[dt][rg * 4 + 0] * inv);
        v4.y = f2bf(oacc[dt][rg * 4 + 1] * inv);
        v4.z = f2bf(oacc[dt][rg * 4 + 2] * inv);
        v4.w = f2bf(oacc[dt][rg * 4 + 3] * inv);
        *(ushort4*)(dst + dt * 32 + rg * 8 + 4 * h5) = v4;
      }
  }
}

// ---------------- launch ----------------
extern "C" void kernel_launch(void* const* d_in, const int* in_sizes, int n_in,
                              void* d_out, int out_size, void* d_ws, size_t ws_size,
                              hipStream_t stream) {
  const int* positions = (const int*)d_in[0];
  const float* hidden  = (const float*)d_in[1];
  const float* w_qkv   = (const float*)d_in[2];
  const float* w_o     = (const float*)d_in[3];
  const float* rms_w   = (const float*)d_in[4];
  float* out = (float*)d_out;

  // byte layout (72 MB): [qkv 32M][hb 16M][wqkvb 16M][wob 8M]
  unsigned short* qkv   = (unsigned short*)d_ws;                   // [4096][4096]
  unsigned short* hb    = qkv + (size_t)M_TOK * OUTQKV;            // [4096][2048]
  unsigned short* wqkvb = hb + (size_t)M_TOK * HIDDEN;             // [4096][2048]
  unsigned short* wob   = wqkvb + (size_t)OUTQKV * HIDDEN;         // [2048][2048]
  unsigned short* qa    = hb;                                      // alias after gemm1
  unsigned short* ka    = wqkvb;                                   // alias after gemm1
  unsigned short* vat   = wqkvb + (size_t)B_SZ * NKV * T_SEQ * HD;
  unsigned short* ob    = qkv;                                     // alias after v_transpose

  const int prep_items = SEG0 + SEG1 + SEG2;
  prep_kernel<<<prep_items / 256, 256, 0, stream>>>(hidden, w_qkv, w_o, hb, wqkvb, wob);
  gemm8<8, unsigned short>
      <<<256, 512, 0, stream>>>(hb, wqkvb, qkv, M_TOK, OUTQKV, HIDDEN);
  norm_rope_kernel<<<M_TOK, 64, 0, stream>>>(qkv, positions, rms_w, qa, ka);
  v_transpose<<<dim3(T_SEQ / 64, NKV, B_SZ), 256, 0, stream>>>(qkv, vat);
  attn_kernel<<<256, 256, 0, stream>>>(qa, ka, vat, ob);
  gemm8<4, float>
      <<<256, 512, 0, stream>>>(ob, wob, out, M_TOK, HIDDEN, QSIZE);
}